// Round 11
// baseline (300.763 us; speedup 1.0000x reference)
//
#include <hip/hip_runtime.h>

typedef __attribute__((ext_vector_type(4))) float f32x4;
typedef __attribute__((ext_vector_type(8))) short bf16x8;
typedef __attribute__((ext_vector_type(4))) unsigned short u16x4;

static __device__ __forceinline__ unsigned short f2bf(float f) {
    union { float f; unsigned int u; } a; a.f = f;
    unsigned int u = a.u;
    unsigned int r = (u + 0x7FFFu + ((u >> 16) & 1u)) >> 16;
    return (unsigned short)r;
}
static __device__ __forceinline__ float bf2f(unsigned short h) {
    union { unsigned int u; float f; } a; a.u = ((unsigned int)h) << 16;
    return a.f;
}
static __device__ __forceinline__ unsigned lds_off(const void* p) {
    return (unsigned)(unsigned long long)(const __attribute__((address_space(3))) void*)p;
}

// ---------------- convert x (fp32 -> bf16), vectorized ----------------
__global__ __launch_bounds__(256) void cvt_f32_bf16(const float* __restrict__ in,
                                                    unsigned short* __restrict__ out) {
    long long i = ((long long)blockIdx.x * 256 + threadIdx.x) * 4;
    float4 f = *(const float4*)(in + i);
    u16x4 u;
    u[0] = f2bf(f.x); u[1] = f2bf(f.y); u[2] = f2bf(f.z); u[3] = f2bf(f.w);
    *(u16x4*)(out + i) = u;
}

// ---------------- transpose W [1024][1024] f32 -> Wt [1024][1024] bf16 ----------------
__global__ __launch_bounds__(256) void transpose_w(const float* __restrict__ W0,
                                                   const float* __restrict__ W1,
                                                   const float* __restrict__ W2,
                                                   unsigned short* __restrict__ Wt) {
    __shared__ float t[32][33];
    int mat = blockIdx.z;
    const float* W = (mat == 0) ? W0 : (mat == 1) ? W1 : W2;
    unsigned short* out = Wt + (long long)mat * 1024 * 1024;
    int n0 = blockIdx.x * 32, k0 = blockIdx.y * 32;
    int tx = threadIdx.x, ty = threadIdx.y;   // 32 x 8
#pragma unroll
    for (int q = 0; q < 4; ++q)
        t[ty + 8 * q][tx] = W[(long long)(k0 + ty + 8 * q) * 1024 + n0 + tx];
    __syncthreads();
#pragma unroll
    for (int q = 0; q < 4; ++q)
        out[(long long)(n0 + ty + 8 * q) * 1024 + k0 + tx] = f2bf(t[tx][ty + 8 * q]);
}

// ====== 256x256 B^T GEMM, BK=64, T14 reg-staged A + deep-lead B, 1 barrier/tile ======
// 512 threads, 8 waves (2M x 4N). LDS: A bufs [0,64K), B bufs [64K,128K), 32 KB/buf.
// Per tile t: at top, issue A(t+1) global->reg (4x16B/thread) and B(t+1) global_load_lds
// (full-tile lead for both). End of tile: ds_write A(t+1) (drained by Q4's lgkmcnt(0)),
// vmcnt(0) for B (issued ~1 tile earlier -> no real wait), ONE barrier publishes both.
// A publication is same-wave-reg + writer-lgkm0 + barrier => no cross-wave vmcnt races.
// OUT_MODE: 0 = bf16 out, 1 = f32 out.  BIAS_MODE: 0 none, 1 bias[n], 2 bias[m].
#define GBM 256
#define GBN 256

template<int OUT_MODE, int BIAS_MODE>
__global__ __launch_bounds__(512, 2) void gemmt14(
    const unsigned short* __restrict__ A, int lda, long long strideA,
    const unsigned short* __restrict__ B, int ldb, long long strideB,
    void* __restrict__ Cv, int ldc, long long strideC,
    const float* __restrict__ bias, int K, float scale)
{
    __shared__ __align__(16) char lds[131072];

    // ---- bijective XCD swizzle (all grids here have nwg % 8 == 0) ----
    const int gx = gridDim.x, gy = gridDim.y;
    int lin = blockIdx.x + gx * (blockIdx.y + gy * blockIdx.z);
    const int nwg = gx * gy * gridDim.z;
    const int qch = nwg >> 3;
    int swz = (lin & 7) * qch + (lin >> 3);
    const int bx = swz % gx; int t2 = swz / gx;
    const int by = t2 % gy;  const int bz = t2 / gy;

    const unsigned short* Ag = A + (long long)bz * strideA;
    const unsigned short* Bg = B + (long long)bz * strideB;
    const int m0 = by * GBM, n0 = bx * GBN;

    const int tid  = threadIdx.x;
    const int lane = tid & 63, w = tid >> 6;      // 8 waves
    const int wm = w >> 2, wn = w & 3;            // wave rows: wm*128, cols: wn*64
    const int l15 = lane & 15, l4 = lane >> 4;

    // staging geometry: rows of 128 B (64 bf16); thread covers 4 chunks of 16 B.
    // lane -> row lane>>3, phys slot lane&7; source slot pre-swizzled (lane&7)^(lane>>3)
    // so LDS row r phys slot c holds logical slot c ^ (r&7).
    const int sr = lane >> 3;
    const int ss = (lane & 7) ^ sr;
    const unsigned short* Asrc = Ag + (long long)(m0 + w * 8 + sr) * lda + ss * 8;
    const unsigned short* Bsrc = Bg + (long long)(n0 + w * 8 + sr) * ldb + ss * 8;

    // A reg-stage: chunk j covers rows j*64 .. j*64+63 (this thread's row within it).
    const unsigned short* AsrcJ[4];
    unsigned awr[4];
#pragma unroll
    for (int j = 0; j < 4; ++j) {
        AsrcJ[j] = Asrc + (long long)(j * 64) * lda;
        awr[j]   = (unsigned)((j * 64 + w * 8 + sr) * 128 + (lane & 7) * 16);
    }
    bf16x8 areg[4];

    f32x4 acc[8][4] = {};

    // B staging via global_load_lds: half h covers rows h*128..h*128+127 (2 instr).
    auto stageB = [&](int p, int kt, int h) {
#pragma unroll
        for (int i = 0; i < 2; ++i)
            __builtin_amdgcn_global_load_lds(
                (const __attribute__((address_space(1))) void*)(Bsrc + (long long)(h * 128 + i * 64) * ldb + kt),
                (__attribute__((address_space(3))) void*)(lds + 65536 + p * 32768 + (h * 128 + i * 64 + w * 8) * 128), 16, 0, 0);
    };

    // read addressing: row r holds logical 16B slot q at LDS slot q ^ (r&7).
    const unsigned ldsb = lds_off(lds);
    const unsigned as0  = (unsigned)(((l4    ) ^ (l15 & 7)) * 16);
    const unsigned as1  = (unsigned)(((l4 + 4) ^ (l15 & 7)) * 16);
    const unsigned aRow = (unsigned)((wm * 128 + l15) * 128);
    const unsigned bRow = (unsigned)((wn * 64 + l15) * 128);

    bf16x8 aA[4], aB[4], aC[4], aD[4], bA[4], bB[4];
    auto readA = [&](bf16x8 (&af)[4], int p, int mh, int ks) {
        unsigned base = ldsb + (unsigned)(p * 32768) + aRow + (unsigned)(mh * 8192) + (ks ? as1 : as0);
#pragma unroll
        for (int fi = 0; fi < 4; ++fi) {
            unsigned off = base + (unsigned)(fi * 2048);
            asm volatile("ds_read_b128 %0, %1" : "=v"(af[fi]) : "v"(off));
        }
    };
    auto readB = [&](bf16x8 (&bf)[4], int p, int ks) {
        unsigned base = ldsb + 65536u + (unsigned)(p * 32768) + bRow + (ks ? as1 : as0);
#pragma unroll
        for (int nj = 0; nj < 4; ++nj) {
            unsigned off = base + (unsigned)(nj * 2048);
            asm volatile("ds_read_b128 %0, %1" : "=v"(bf[nj]) : "v"(off));
        }
    };
    auto mfma16 = [&](int mh, bf16x8 (&af)[4], bf16x8 (&bf)[4]) {
#pragma unroll
        for (int fi = 0; fi < 4; ++fi)
#pragma unroll
            for (int nj = 0; nj < 4; ++nj)
                acc[mh * 4 + fi][nj] = __builtin_amdgcn_mfma_f32_16x16x32_bf16(
                    af[fi], bf[nj], acc[mh * 4 + fi][nj], 0, 0, 0);
    };

#define VMCNT0 asm volatile("s_waitcnt vmcnt(0)" ::: "memory")
#define LGKM8  asm volatile("s_waitcnt lgkmcnt(8)" ::: "memory")
#define LGKM4  asm volatile("s_waitcnt lgkmcnt(4)" ::: "memory")
#define LGKM0  asm volatile("s_waitcnt lgkmcnt(0)" ::: "memory")
#define SCHED0 __builtin_amdgcn_sched_barrier(0)
#define BARR   __builtin_amdgcn_s_barrier()
#define PRIO1  __builtin_amdgcn_s_setprio(1)
#define PRIO0  __builtin_amdgcn_s_setprio(0)

    const int NT = K >> 6;
    // prologue: stage tile 0 into buf 0 (A via reg->ds_write, B via gll), publish.
#pragma unroll
    for (int j = 0; j < 4; ++j) areg[j] = *(const bf16x8*)(AsrcJ[j]);
    stageB(0, 0, 0); stageB(0, 0, 1);
#pragma unroll
    for (int j = 0; j < 4; ++j) *(bf16x8*)(&lds[awr[j]]) = areg[j];   // compiler waits areg
    LGKM0; VMCNT0; BARR; SCHED0;

    for (int t = 0; t < NT; ++t) {
        const int p = t & 1, q = p ^ 1;
        const int kt1 = (t + 1) << 6;
        const bool s1 = (t + 1) < NT;
        // tile top: issue next tile's A (to regs) and B (to LDS buf q) — full-tile lead.
        if (s1) {
#pragma unroll
            for (int j = 0; j < 4; ++j) areg[j] = *(const bf16x8*)(AsrcJ[j] + kt1);
            stageB(q, kt1, 0); stageB(q, kt1, 1);
        }
        // compute tile t from buf p, LDS reads counted-lgkm-pipelined under MFMA.
        readA(aA, p, 0, 0); readB(bA, p, 0);
        readA(aC, p, 0, 1); readB(bB, p, 1);
        LGKM8; SCHED0; PRIO1; mfma16(0, aA, bA); PRIO0;      // Q1 (mh0,ks0)
        readA(aB, p, 1, 0); readA(aD, p, 1, 1);
        LGKM8; SCHED0; PRIO1; mfma16(0, aC, bB); PRIO0;      // Q2 (mh0,ks1)
        LGKM4; SCHED0; PRIO1; mfma16(1, aB, bA); PRIO0;      // Q3 (mh1,ks0)
        if (s1) {
#pragma unroll
            for (int j = 0; j < 4; ++j) *(bf16x8*)(&lds[(q * 32768) + awr[j]]) = areg[j];
        }
        LGKM0; SCHED0; PRIO1; mfma16(1, aD, bB); PRIO0;      // Q4 (drains aD + A-writes)
        if (s1) { VMCNT0; }                                  // B(t+1): issued ~1 tile ago
        BARR; SCHED0;                                        // publish buf q
    }

    // epilogue: C/D frag layout col = lane&15 (N), row = (lane>>4)*4 + r (M)
    const float* bias_v = bias;
    asm volatile("" : "+s"(bias_v));   // keep bias loads out of the counted region
    unsigned short* Cb = (unsigned short*)Cv;
    float* Cf = (float*)Cv;
    long long cbase = (long long)bz * strideC;
#pragma unroll
    for (int mh = 0; mh < 2; ++mh)
#pragma unroll
    for (int fi = 0; fi < 4; ++fi) {
#pragma unroll
        for (int nj = 0; nj < 4; ++nj) {
            int n = n0 + wn * 64 + nj * 16 + l15;
            float bn = (BIAS_MODE == 1) ? bias_v[n] : 0.0f;
#pragma unroll
            for (int r = 0; r < 4; ++r) {
                int m = m0 + wm * 128 + mh * 64 + fi * 16 + l4 * 4 + r;
                float v = acc[mh * 4 + fi][nj][r] * scale + bn;
                if (BIAS_MODE == 2) v += bias_v[m];
                long long idx = cbase + (long long)m * ldc + n;
                if (OUT_MODE == 0) Cb[idx] = f2bf(v);
                else               Cf[idx] = v;
            }
        }
    }
}

// ------- row softmax over bf16 scores, in place: S[row][2048] bf16 -> P bf16 -------
__global__ __launch_bounds__(256) void softmax_rows_bf16(unsigned short* __restrict__ S) {
    int row  = blockIdx.x * 4 + (threadIdx.x >> 6);
    int lane = threadIdx.x & 63;
    unsigned short* Srow = S + (long long)row * 2048;
    float v[32];
    float mx = -1e30f;
#pragma unroll
    for (int j = 0; j < 4; ++j) {
        bf16x8 h = *(const bf16x8*)(Srow + j * 512 + lane * 8);
#pragma unroll
        for (int e = 0; e < 8; ++e) {
            float f = bf2f((unsigned short)h[e]);
            v[j * 8 + e] = f;
            mx = fmaxf(mx, f);
        }
    }
#pragma unroll
    for (int o = 32; o; o >>= 1) mx = fmaxf(mx, __shfl_xor(mx, o));
    float sum = 0.0f;
#pragma unroll
    for (int e = 0; e < 32; ++e) {
        v[e] = __expf(v[e] - mx);
        sum += v[e];
    }
#pragma unroll
    for (int o = 32; o; o >>= 1) sum += __shfl_xor(sum, o);
    float inv = 1.0f / sum;
#pragma unroll
    for (int j = 0; j < 4; ++j) {
        bf16x8 h;
#pragma unroll
        for (int e = 0; e < 8; ++e) h[e] = (short)f2bf(v[j * 8 + e] * inv);
        *(bf16x8*)(Srow + j * 512 + lane * 8) = h;
    }
}

extern "C" void kernel_launch(void* const* d_in, const int* in_sizes, int n_in,
                              void* d_out, int out_size, void* d_ws, size_t ws_size,
                              hipStream_t stream) {
    (void)in_sizes; (void)n_in; (void)out_size; (void)ws_size;
    const float* x  = (const float*)d_in[0];
    const float* Wq = (const float*)d_in[1];
    const float* bq = (const float*)d_in[2];
    const float* Wk = (const float*)d_in[3];
    const float* bk = (const float*)d_in[4];
    const float* Wv = (const float*)d_in[5];
    const float* bv = (const float*)d_in[6];

    // workspace layout (bytes) — peak ~166 MiB
    char* ws = (char*)d_ws;
    unsigned short* Wt  = (unsigned short*)ws;                       //   6,291,456 B (q,k,v)
    unsigned short* Qb  = (unsigned short*)(ws + 6291456);           //  33,554,432
    unsigned short* Kb  = (unsigned short*)(ws + 39845888);          //  33,554,432
    unsigned short* Vt  = (unsigned short*)(ws + 73400320);          //  33,554,432
    unsigned short* xb  = (unsigned short*)(ws + 106954752);         //  33,554,432 (dead after V proj)
    unsigned short* Sb  = (unsigned short*)(ws + 106954752);         //  67,108,864 (bf16 scores, overlays xb)

    // 1) convert x -> bf16
    cvt_f32_bf16<<<dim3(16384), dim3(256), 0, stream>>>(x, xb);
    // 2) W^T -> bf16 (3 mats)
    transpose_w<<<dim3(32, 32, 3), dim3(32, 8), 0, stream>>>(Wq, Wk, Wv, Wt);

    // 3) Q = xb @ Wq + bq   -> bf16 [16384][1024]
    gemmt14<0, 1><<<dim3(4, 64, 1), dim3(512), 0, stream>>>(
        xb, 1024, 0, Wt, 1024, 0, Qb, 1024, 0, bq, 1024, 1.0f);
    // 4) K
    gemmt14<0, 1><<<dim3(4, 64, 1), dim3(512), 0, stream>>>(
        xb, 1024, 0, Wt + 1048576, 1024, 0, Kb, 1024, 0, bk, 1024, 1.0f);
    // 5) Vt[d][m] = sum_k Wvt[d][k] xb[m][k] + bv[d]  -> bf16 [1024][16384]
    gemmt14<0, 2><<<dim3(64, 4, 1), dim3(512), 0, stream>>>(
        Wt + 2097152, 1024, 0, xb, 1024, 0, Vt, 16384, 0, bv, 1024, 1.0f);

    // 6) scores: S[b][q][kv] = (Q @ K^T) * 1/32   -> bf16 (xb dead now)
    gemmt14<0, 0><<<dim3(8, 8, 8), dim3(512), 0, stream>>>(
        Qb, 1024, 2097152LL, Kb, 1024, 2097152LL,
        Sb, 2048, 4194304LL, nullptr, 1024, 0.03125f);

    // 7) softmax rows in place (bf16 -> bf16)
    softmax_rows_bf16<<<dim3(4096), dim3(256), 0, stream>>>(Sb);

    // 8) out[b][q][d] = P @ V = sum_kv P[q][kv] * Vt[d][b*2048+kv]
    gemmt14<1, 0><<<dim3(4, 8, 8), dim3(512), 0, stream>>>(
        Sb, 2048, 4194304LL,
        Vt, 16384, 2048LL,
        d_out, 1024, 2097152LL, nullptr, 2048, 1.0f);
}

// Round 12
// 270.873 us; speedup vs baseline: 1.1103x; 1.1103x over previous
//
#include <hip/hip_runtime.h>
#include <hip/hip_fp8.h>

typedef __attribute__((ext_vector_type(4))) float f32x4;
typedef __attribute__((ext_vector_type(8))) short bf16x8;
typedef __attribute__((ext_vector_type(4))) unsigned short u16x4;

static __device__ __forceinline__ unsigned short f2bf(float f) {
    union { float f; unsigned int u; } a; a.f = f;
    unsigned int u = a.u;
    unsigned int r = (u + 0x7FFFu + ((u >> 16) & 1u)) >> 16;
    return (unsigned short)r;
}
static __device__ __forceinline__ float bf2f(unsigned short h) {
    union { unsigned int u; float f; } a; a.u = ((unsigned int)h) << 16;
    return a.f;
}
static __device__ __forceinline__ unsigned char f2fp8(float f) {
    __hip_fp8_e4m3 h(f);
    return *reinterpret_cast<const unsigned char*>(&h);
}
static __device__ __forceinline__ unsigned lds_off(const void* p) {
    return (unsigned)(unsigned long long)(const __attribute__((address_space(3))) void*)p;
}

// ---------------- convert x (fp32 -> bf16), vectorized ----------------
__global__ __launch_bounds__(256) void cvt_f32_bf16(const float* __restrict__ in,
                                                    unsigned short* __restrict__ out) {
    long long i = ((long long)blockIdx.x * 256 + threadIdx.x) * 4;
    float4 f = *(const float4*)(in + i);
    u16x4 u;
    u[0] = f2bf(f.x); u[1] = f2bf(f.y); u[2] = f2bf(f.z); u[3] = f2bf(f.w);
    *(u16x4*)(out + i) = u;
}

// ---------------- transpose W [1024][1024] f32 -> Wt [1024][1024] bf16 ----------------
__global__ __launch_bounds__(256) void transpose_w(const float* __restrict__ W0,
                                                   const float* __restrict__ W1,
                                                   const float* __restrict__ W2,
                                                   unsigned short* __restrict__ Wt) {
    __shared__ float t[32][33];
    int mat = blockIdx.z;
    const float* W = (mat == 0) ? W0 : (mat == 1) ? W1 : W2;
    unsigned short* out = Wt + (long long)mat * 1024 * 1024;
    int n0 = blockIdx.x * 32, k0 = blockIdx.y * 32;
    int tx = threadIdx.x, ty = threadIdx.y;   // 32 x 8
#pragma unroll
    for (int q = 0; q < 4; ++q)
        t[ty + 8 * q][tx] = W[(long long)(k0 + ty + 8 * q) * 1024 + n0 + tx];
    __syncthreads();
#pragma unroll
    for (int q = 0; q < 4; ++q)
        out[(long long)(n0 + ty + 8 * q) * 1024 + k0 + tx] = f2bf(t[tx][ty + 8 * q]);
}

#define SCHED0 __builtin_amdgcn_sched_barrier(0)
#define BARR   __builtin_amdgcn_s_barrier()
#define PRIO1  __builtin_amdgcn_s_setprio(1)
#define PRIO0  __builtin_amdgcn_s_setprio(0)
#define VMCNT4 asm volatile("s_waitcnt vmcnt(4)" ::: "memory")
#define VMCNT2 asm volatile("s_waitcnt vmcnt(2)" ::: "memory")
#define VMCNT0 asm volatile("s_waitcnt vmcnt(0)" ::: "memory")
#define LGKM12 asm volatile("s_waitcnt lgkmcnt(12)" ::: "memory")
#define LGKM8  asm volatile("s_waitcnt lgkmcnt(8)" ::: "memory")
#define LGKM4  asm volatile("s_waitcnt lgkmcnt(4)" ::: "memory")
#define LGKM0  asm volatile("s_waitcnt lgkmcnt(0)" ::: "memory")

// ====== 256x256 B^T GEMM (bf16), BK=64, counted-vmcnt, 2 barriers/tile (round-10) ======
// OUT_MODE: 0 = bf16 out, 1 = f32 out, 2 = fp8 e4m3 out (value*16).
// BIAS_MODE: 0 none, 1 bias[n], 2 bias[m].
#define GBM 256
#define GBN 256

template<int OUT_MODE, int BIAS_MODE>
__global__ __launch_bounds__(512, 2) void gemmcv(
    const unsigned short* __restrict__ A, int lda, long long strideA,
    const unsigned short* __restrict__ B, int ldb, long long strideB,
    void* __restrict__ Cv, int ldc, long long strideC,
    const float* __restrict__ bias, int K, float scale)
{
    __shared__ __align__(16) char lds[131072];

    const int gx = gridDim.x, gy = gridDim.y;
    int lin = blockIdx.x + gx * (blockIdx.y + gy * blockIdx.z);
    const int nwg = gx * gy * gridDim.z;
    const int qch = nwg >> 3;
    int swz = (lin & 7) * qch + (lin >> 3);
    const int bx = swz % gx; int t2 = swz / gx;
    const int by = t2 % gy;  const int bz = t2 / gy;

    const unsigned short* Ag = A + (long long)bz * strideA;
    const unsigned short* Bg = B + (long long)bz * strideB;
    const int m0 = by * GBM, n0 = bx * GBN;

    const int tid  = threadIdx.x;
    const int lane = tid & 63, w = tid >> 6;
    const int wm = w >> 2, wn = w & 3;
    const int l15 = lane & 15, l4 = lane >> 4;

    const int sr = lane >> 3;
    const int ss = (lane & 7) ^ sr;
    const unsigned short* Asrc = Ag + (long long)(m0 + w * 8 + sr) * lda + ss * 8;
    const unsigned short* Bsrc = Bg + (long long)(n0 + w * 8 + sr) * ldb + ss * 8;

    f32x4 acc[8][4] = {};

    auto stageA = [&](int p, int kt, int h) {
#pragma unroll
        for (int i = 0; i < 2; ++i)
            __builtin_amdgcn_global_load_lds(
                (const __attribute__((address_space(1))) void*)(Asrc + (long long)(h * 128 + i * 64) * lda + kt),
                (__attribute__((address_space(3))) void*)(lds + p * 32768 + (h * 128 + i * 64 + w * 8) * 128), 16, 0, 0);
    };
    auto stageB = [&](int p, int kt, int h) {
#pragma unroll
        for (int i = 0; i < 2; ++i)
            __builtin_amdgcn_global_load_lds(
                (const __attribute__((address_space(1))) void*)(Bsrc + (long long)(h * 128 + i * 64) * ldb + kt),
                (__attribute__((address_space(3))) void*)(lds + 65536 + p * 32768 + (h * 128 + i * 64 + w * 8) * 128), 16, 0, 0);
    };

    const unsigned ldsb = lds_off(lds);
    const unsigned as0  = (unsigned)(((l4    ) ^ (l15 & 7)) * 16);
    const unsigned as1  = (unsigned)(((l4 + 4) ^ (l15 & 7)) * 16);
    const unsigned aRow = (unsigned)((wm * 128 + l15) * 128);
    const unsigned bRow = (unsigned)((wn * 64 + l15) * 128);

    bf16x8 aA[4], aB[4], aC[4], aD[4], bA[4], bB[4];
    auto readA = [&](bf16x8 (&af)[4], int p, int mh, int ks) {
        unsigned base = ldsb + (unsigned)(p * 32768) + aRow + (unsigned)(mh * 8192) + (ks ? as1 : as0);
#pragma unroll
        for (int fi = 0; fi < 4; ++fi) {
            unsigned off = base + (unsigned)(fi * 2048);
            asm volatile("ds_read_b128 %0, %1" : "=v"(af[fi]) : "v"(off));
        }
    };
    auto readB = [&](bf16x8 (&bf)[4], int p, int ks) {
        unsigned base = ldsb + 65536u + (unsigned)(p * 32768) + bRow + (ks ? as1 : as0);
#pragma unroll
        for (int nj = 0; nj < 4; ++nj) {
            unsigned off = base + (unsigned)(nj * 2048);
            asm volatile("ds_read_b128 %0, %1" : "=v"(bf[nj]) : "v"(off));
        }
    };
    auto mfma16 = [&](int mh, bf16x8 (&af)[4], bf16x8 (&bf)[4]) {
#pragma unroll
        for (int fi = 0; fi < 4; ++fi)
#pragma unroll
            for (int nj = 0; nj < 4; ++nj)
                acc[mh * 4 + fi][nj] = __builtin_amdgcn_mfma_f32_16x16x32_bf16(
                    af[fi], bf[nj], acc[mh * 4 + fi][nj], 0, 0, 0);
    };

    const int NT = K >> 6;
    stageB(0, 0, 0); stageB(0, 0, 1); stageA(0, 0, 0); stageA(0, 0, 1);

    for (int t = 0; t < NT; ++t) {
        const int p = t & 1, q = p ^ 1;
        const int kt1 = (t + 1) << 6;
        const bool s1 = (t + 1) < NT;
        VMCNT2; BARR; SCHED0;
        if (s1) { stageB(q, kt1, 0); stageB(q, kt1, 1); }
        readA(aA, p, 0, 0); readB(bA, p, 0);
        readA(aC, p, 0, 1); readB(bB, p, 1);
        LGKM8; SCHED0; PRIO1; mfma16(0, aA, bA); PRIO0;
        if (s1) { VMCNT4; } else { VMCNT0; }
        BARR; SCHED0;
        if (s1) { stageA(q, kt1, 0); stageA(q, kt1, 1); }
        readA(aB, p, 1, 0); readA(aD, p, 1, 1);
        LGKM8; SCHED0; PRIO1; mfma16(0, aC, bB); PRIO0;
        LGKM4; SCHED0; PRIO1; mfma16(1, aB, bA); PRIO0;
        LGKM0; SCHED0; PRIO1; mfma16(1, aD, bB); PRIO0;
    }

    const float* bias_v = bias;
    asm volatile("" : "+s"(bias_v));
    unsigned short* Cb = (unsigned short*)Cv;
    unsigned char*  C8 = (unsigned char*)Cv;
    float* Cf = (float*)Cv;
    long long cbase = (long long)bz * strideC;
#pragma unroll
    for (int mh = 0; mh < 2; ++mh)
#pragma unroll
    for (int fi = 0; fi < 4; ++fi) {
#pragma unroll
        for (int nj = 0; nj < 4; ++nj) {
            int n = n0 + wn * 64 + nj * 16 + l15;
            float bn = (BIAS_MODE == 1) ? bias_v[n] : 0.0f;
#pragma unroll
            for (int r = 0; r < 4; ++r) {
                int m = m0 + wm * 128 + mh * 64 + fi * 16 + l4 * 4 + r;
                float v = acc[mh * 4 + fi][nj][r] * scale + bn;
                if (BIAS_MODE == 2) v += bias_v[m];
                long long idx = cbase + (long long)m * ldc + n;
                if (OUT_MODE == 0)      Cb[idx] = f2bf(v);
                else if (OUT_MODE == 1) Cf[idx] = v;
                else                    C8[idx] = f2fp8(v * 16.0f);
            }
        }
    }
}

// ====== 256x256 B^T GEMM (fp8 e4m3 inputs), BK=128 elems, same byte geometry ======
// LDS row = 128 fp8 = 128B.  Swizzle: logical 32B group g of row R at phys group
// g ^ (R&3); 16B halves swapped by bit (R>>2)&1.  ds_read_b64 frags, <=2 lanes/bank.
// Output bf16 (scores), scale folds the fp8 x16 scales: 1/8192.
__global__ __launch_bounds__(512, 2) void gemmf8(
    const unsigned char* __restrict__ A, int lda, long long strideA,
    const unsigned char* __restrict__ B, int ldb, long long strideB,
    unsigned short* __restrict__ C, int ldc, long long strideC,
    int K, float scale)
{
    __shared__ __align__(16) char lds[131072];

    const int gx = gridDim.x, gy = gridDim.y;
    int lin = blockIdx.x + gx * (blockIdx.y + gy * blockIdx.z);
    const int nwg = gx * gy * gridDim.z;
    const int qch = nwg >> 3;
    int swz = (lin & 7) * qch + (lin >> 3);
    const int bx = swz % gx; int t2 = swz / gx;
    const int by = t2 % gy;  const int bz = t2 / gy;

    const unsigned char* Ag = A + (long long)bz * strideA;
    const unsigned char* Bg = B + (long long)bz * strideB;
    const int m0 = by * GBM, n0 = bx * GBN;

    const int tid  = threadIdx.x;
    const int lane = tid & 63, w = tid >> 6;
    const int wm = w >> 2, wn = w & 3;
    const int l15 = lane & 15, l4 = lane >> 4;

    // staging source pre-swizzle: lane -> row sr=lane>>3, phys 16B slot c=lane&7.
    // logical 16B slot = (((c>>1) ^ (sr&3)) << 1) | ((c&1) ^ (lane>>5))
    const int sr = lane >> 3;
    const int c7 = lane & 7;
    const int ss8 = (((((c7 >> 1) ^ (sr & 3)) << 1) | ((c7 & 1) ^ ((lane >> 5) & 1)))) * 16;
    const unsigned char* Asrc = Ag + (long long)(m0 + w * 8 + sr) * lda + ss8;
    const unsigned char* Bsrc = Bg + (long long)(n0 + w * 8 + sr) * ldb + ss8;

    f32x4 acc[8][4] = {};

    auto stageA = [&](int p, int kt, int h) {
#pragma unroll
        for (int i = 0; i < 2; ++i)
            __builtin_amdgcn_global_load_lds(
                (const __attribute__((address_space(1))) void*)(Asrc + (long long)(h * 128 + i * 64) * lda + kt),
                (__attribute__((address_space(3))) void*)(lds + p * 32768 + (h * 128 + i * 64 + w * 8) * 128), 16, 0, 0);
    };
    auto stageB = [&](int p, int kt, int h) {
#pragma unroll
        for (int i = 0; i < 2; ++i)
            __builtin_amdgcn_global_load_lds(
                (const __attribute__((address_space(1))) void*)(Bsrc + (long long)(h * 128 + i * 64) * ldb + kt),
                (__attribute__((address_space(3))) void*)(lds + 65536 + p * 32768 + (h * 128 + i * 64 + w * 8) * 128), 16, 0, 0);
    };

    // frag reads: lane supplies 8 fp8 at logical byte ks*32 + l4*8 of its row.
    // phys within row = ((ks ^ (l15&3))<<5) + ((l4<<3) ^ (((l15>>2)&1)<<4))
    const unsigned ldsb  = lds_off(lds);
    const unsigned kbase = (unsigned)((l4 << 3) ^ (((l15 >> 2) & 1) << 4));
    unsigned kk[4];
#pragma unroll
    for (int ks = 0; ks < 4; ++ks) kk[ks] = (unsigned)((ks ^ (l15 & 3)) << 5) + kbase;
    const unsigned aRow = (unsigned)((wm * 128 + l15) * 128);
    const unsigned bRow = (unsigned)((wn * 64 + l15) * 128) + 65536u;

    long a0[4][4], a1[4][4], bb[4][4];   // [ks][frag]
    auto readA = [&](long (&af)[4], int p, int mh, int ks) {
        unsigned base = ldsb + (unsigned)(p * 32768) + aRow + (unsigned)(mh * 8192) + kk[ks];
#pragma unroll
        for (int fi = 0; fi < 4; ++fi) {
            unsigned off = base + (unsigned)(fi * 2048);
            asm volatile("ds_read_b64 %0, %1" : "=v"(af[fi]) : "v"(off));
        }
    };
    auto readB = [&](long (&bf)[4], int p, int ks) {
        unsigned base = ldsb + (unsigned)(p * 32768) + bRow + kk[ks];
#pragma unroll
        for (int nj = 0; nj < 4; ++nj) {
            unsigned off = base + (unsigned)(nj * 2048);
            asm volatile("ds_read_b64 %0, %1" : "=v"(bf[nj]) : "v"(off));
        }
    };
    auto mf = [&](int mh, long (&af)[4], long (&bf)[4]) {
#pragma unroll
        for (int fi = 0; fi < 4; ++fi)
#pragma unroll
            for (int nj = 0; nj < 4; ++nj)
                acc[mh * 4 + fi][nj] = __builtin_amdgcn_mfma_f32_16x16x32_fp8_fp8(
                    af[fi], bf[nj], acc[mh * 4 + fi][nj], 0, 0, 0);
    };

    const int NT = K >> 7;               // 128 elements per tile
    stageB(0, 0, 0); stageB(0, 0, 1); stageA(0, 0, 0); stageA(0, 0, 1);

    for (int t = 0; t < NT; ++t) {
        const int p = t & 1, q = p ^ 1;
        const int kt1 = (t + 1) << 7;
        const bool s1 = (t + 1) < NT;
        VMCNT2; BARR; SCHED0;            // publish B(t) + A rows 0..127 (mh0)
        if (s1) { stageB(q, kt1, 0); stageB(q, kt1, 1); }
        readA(a0[0], p, 0, 0); readB(bb[0], p, 0);
        readA(a0[1], p, 0, 1); readB(bb[1], p, 1);
        LGKM8; SCHED0; PRIO1; mf(0, a0[0], bb[0]); PRIO0;     // mh0 ks0
        readA(a0[2], p, 0, 2); readB(bb[2], p, 2);
        LGKM8; SCHED0; PRIO1; mf(0, a0[1], bb[1]); PRIO0;     // mh0 ks1
        if (s1) { VMCNT4; } else { VMCNT0; }
        BARR; SCHED0;                     // publish A rows 128..255 (mh1)
        if (s1) { stageA(q, kt1, 0); stageA(q, kt1, 1); }
        readA(a0[3], p, 0, 3); readB(bb[3], p, 3);
        LGKM8; SCHED0; PRIO1; mf(0, a0[2], bb[2]); PRIO0;     // mh0 ks2
        readA(a1[0], p, 1, 0); readA(a1[1], p, 1, 1);
        LGKM8; SCHED0; PRIO1; mf(0, a0[3], bb[3]); PRIO0;     // mh0 ks3
        readA(a1[2], p, 1, 2); readA(a1[3], p, 1, 3);
        LGKM12; SCHED0; PRIO1; mf(1, a1[0], bb[0]); PRIO0;    // mh1 ks0
        LGKM8;  SCHED0; PRIO1; mf(1, a1[1], bb[1]); PRIO0;    // mh1 ks1
        LGKM4;  SCHED0; PRIO1; mf(1, a1[2], bb[2]); PRIO0;    // mh1 ks2
        LGKM0;  SCHED0; PRIO1; mf(1, a1[3], bb[3]); PRIO0;    // mh1 ks3
    }

    long long cbase = (long long)bz * strideC;
#pragma unroll
    for (int mh = 0; mh < 2; ++mh)
#pragma unroll
    for (int fi = 0; fi < 4; ++fi) {
#pragma unroll
        for (int nj = 0; nj < 4; ++nj) {
            int n = n0 + wn * 64 + nj * 16 + l15;
#pragma unroll
            for (int r = 0; r < 4; ++r) {
                int m = m0 + wm * 128 + mh * 64 + fi * 16 + l4 * 4 + r;
                C[cbase + (long long)m * ldc + n] = f2bf(acc[mh * 4 + fi][nj][r] * scale);
            }
        }
    }
}

// ------- row softmax over bf16 scores, in place: S[row][2048] bf16 -> P bf16 -------
__global__ __launch_bounds__(256) void softmax_rows_bf16(unsigned short* __restrict__ S) {
    int row  = blockIdx.x * 4 + (threadIdx.x >> 6);
    int lane = threadIdx.x & 63;
    unsigned short* Srow = S + (long long)row * 2048;
    float v[32];
    float mx = -1e30f;
#pragma unroll
    for (int j = 0; j < 4; ++j) {
        bf16x8 h = *(const bf16x8*)(Srow + j * 512 + lane * 8);
#pragma unroll
        for (int e = 0; e < 8; ++e) {
            float f = bf2f((unsigned short)h[e]);
            v[j * 8 + e] = f;
            mx = fmaxf(mx, f);
        }
    }
#pragma unroll
    for (int o = 32; o; o >>= 1) mx = fmaxf(mx, __shfl_xor(mx, o));
    float sum = 0.0f;
#pragma unroll
    for (int e = 0; e < 32; ++e) {
        v[e] = __expf(v[e] - mx);
        sum += v[e];
    }
#pragma unroll
    for (int o = 32; o; o >>= 1) sum += __shfl_xor(sum, o);
    float inv = 1.0f / sum;
#pragma unroll
    for (int j = 0; j < 4; ++j) {
        bf16x8 h;
#pragma unroll
        for (int e = 0; e < 8; ++e) h[e] = (short)f2bf(v[j * 8 + e] * inv);
        *(bf16x8*)(Srow + j * 512 + lane * 8) = h;
    }
}

extern "C" void kernel_launch(void* const* d_in, const int* in_sizes, int n_in,
                              void* d_out, int out_size, void* d_ws, size_t ws_size,
                              hipStream_t stream) {
    (void)in_sizes; (void)n_in; (void)out_size; (void)ws_size;
    const float* x  = (const float*)d_in[0];
    const float* Wq = (const float*)d_in[1];
    const float* bq = (const float*)d_in[2];
    const float* Wk = (const float*)d_in[3];
    const float* bk = (const float*)d_in[4];
    const float* Wv = (const float*)d_in[5];
    const float* bv = (const float*)d_in[6];

    // workspace layout (bytes) — peak ~134 MiB
    char* ws = (char*)d_ws;
    unsigned short* Wt  = (unsigned short*)ws;                       //   6,291,456 B (q,k,v)
    unsigned char*  Qb8 = (unsigned char*) (ws + 6291456);           //  16,777,216 (fp8, x16)
    unsigned char*  Kb8 = (unsigned char*) (ws + 23068672);          //  16,777,216 (fp8, x16)
    unsigned short* Vt  = (unsigned short*)(ws + 39845888);          //  33,554,432
    unsigned short* xb  = (unsigned short*)(ws + 73400320);          //  33,554,432 (dead after V proj)
    unsigned short* Sb  = (unsigned short*)(ws + 73400320);          //  67,108,864 (bf16 scores, overlays xb)

    // 1) convert x -> bf16
    cvt_f32_bf16<<<dim3(16384), dim3(256), 0, stream>>>(x, xb);
    // 2) W^T -> bf16 (3 mats)
    transpose_w<<<dim3(32, 32, 3), dim3(32, 8), 0, stream>>>(Wq, Wk, Wv, Wt);

    // 3) Q = xb @ Wq + bq   -> fp8 (x16) [16384][1024]
    gemmcv<2, 1><<<dim3(4, 64, 1), dim3(512), 0, stream>>>(
        xb, 1024, 0, Wt, 1024, 0, Qb8, 1024, 0, bq, 1024, 1.0f);
    // 4) K -> fp8 (x16)
    gemmcv<2, 1><<<dim3(4, 64, 1), dim3(512), 0, stream>>>(
        xb, 1024, 0, Wt + 1048576, 1024, 0, Kb8, 1024, 0, bk, 1024, 1.0f);
    // 5) Vt[d][m] = sum_k Wvt[d][k] xb[m][k] + bv[d]  -> bf16 [1024][16384]
    gemmcv<0, 2><<<dim3(64, 4, 1), dim3(512), 0, stream>>>(
        Wt + 2097152, 1024, 0, xb, 1024, 0, Vt, 16384, 0, bv, 1024, 1.0f);

    // 6) scores: S[b][q][kv] = (Q @ K^T)/32 via fp8: acc*(1/8192) -> bf16 (xb dead)
    gemmf8<<<dim3(8, 8, 8), dim3(512), 0, stream>>>(
        Qb8, 1024, 2097152LL, Kb8, 1024, 2097152LL,
        Sb, 2048, 4194304LL, 1024, 1.0f / 8192.0f);

    // 7) softmax rows in place (bf16 -> bf16)
    softmax_rows_bf16<<<dim3(4096), dim3(256), 0, stream>>>(Sb);

    // 8) out[b][q][d] = P @ V = sum_kv P[q][kv] * Vt[d][b*2048+kv]
    gemmcv<1, 0><<<dim3(4, 8, 8), dim3(512), 0, stream>>>(
        Sb, 2048, 4194304LL,
        Vt, 16384, 2048LL,
        d_out, 1024, 2097152LL, nullptr, 2048, 1.0f);
}